// Round 1
// baseline (569.866 us; speedup 1.0000x reference)
//
#include <hip/hip_runtime.h>
#include <hip/hip_bf16.h>

typedef unsigned int u32;
typedef unsigned short u16;

#define N_PTS 100000
#define NSAMP 16

__device__ __forceinline__ float lo2f(u32 u){ return __uint_as_float(u << 16); }
__device__ __forceinline__ float hi2f(u32 u){ return __uint_as_float(u & 0xffff0000u); }
__device__ __forceinline__ float us2f(u16 u){ return __uint_as_float(((u32)u) << 16); }

// Runtime input-dtype probe. Reads only EVEN u16 indices (= low halves if the
// buffer is fp32). fp32: low halves decode as bf16 with random exponents ->
// ~46% exceed 1024 in magnitude. bf16 N(0,1): zero hits.
// Must be called by ALL threads of the block (contains a barrier).
__device__ __forceinline__ bool detect_f32(const u16* __restrict__ xprobe) {
    float f = us2f(xprobe[(threadIdx.x & 63) * 2]);
    int cnt = __syncthreads_count(fabsf(f) > 1024.0f ? 1 : 0);
    return cnt >= 8;
}

// canonical fp32 weight-block offsets (floats, each 16B-aligned)
#define OFF_WQ   0
#define OFF_BQ   4096
#define OFF_WK   4160
#define OFF_BK   8256
#define OFF_WV   8320
#define OFF_BV   12416
#define OFF_WP1  12480
#define OFF_BP1  12492
#define OFF_GP   12496
#define OFF_BP   12500
#define OFF_WP2  12504
#define OFF_BP2  12696
#define OFF_G1   12760
#define OFF_BB1  12824
#define OFF_WA   12888
#define OFF_BA   13400
#define OFF_G2   13408
#define OFF_BB2  13416
#define OFF_WB   13424
#define OFF_BW   13488
#define CW_PAD   16384   /* pad region to 64 KB of floats */

// ---------------------------------------------------------------------------
// K0: canonicalize all small weight arrays to fp32 (handles bf16 or fp32 src)
// ---------------------------------------------------------------------------
__global__ __launch_bounds__(256) void convert_kernel(
    const u16* __restrict__ xprobe,
    const void* s0,  const void* s1,  const void* s2,  const void* s3,
    const void* s4,  const void* s5,  const void* s6,  const void* s7,
    const void* s8,  const void* s9,  const void* s10, const void* s11,
    const void* s12, const void* s13, const void* s14, const void* s15,
    const void* s16, const void* s17, const void* s18, const void* s19,
    float* __restrict__ cw)
{
    bool isf32 = detect_f32(xprobe);
    const void* srcs[20] = {s0,s1,s2,s3,s4,s5,s6,s7,s8,s9,s10,s11,s12,s13,s14,s15,s16,s17,s18,s19};
    const int sizes[20] = {4096,64,4096,64,4096,64,9,3,3,3,192,64,64,64,512,8,8,8,64,8};
    const int offs[20]  = {OFF_WQ,OFF_BQ,OFF_WK,OFF_BK,OFF_WV,OFF_BV,OFF_WP1,OFF_BP1,OFF_GP,OFF_BP,
                           OFF_WP2,OFF_BP2,OFF_G1,OFF_BB1,OFF_WA,OFF_BA,OFF_G2,OFF_BB2,OFF_WB,OFF_BW};
    int tid = threadIdx.x + blockIdx.x * 256;
    int stride = gridDim.x * 256;
    for (int a = 0; a < 20; a++) {
        const void* s = srcs[a];
        for (int k = tid; k < sizes[a]; k += stride)
            cw[offs[a] + k] = isf32 ? ((const float*)s)[k] : us2f(((const u16*)s)[k]);
    }
}

// ---------------------------------------------------------------------------
// K1: Q = x@Wq+bq ; K = x@Wk+bk ; V = x@Wv+bv  (fp32, register-blocked)
// Each wave handles 8 rows; lane c owns output column c of all 8 rows.
// Lane c preloads x[row][c]; x[row][k] is broadcast to the wave via __shfl,
// so each weight element is loaded once per 8 rows (24x less L1 traffic
// than the previous one-row-per-thread version).
// Block = 256 = 4 waves = 32 rows; grid = 100000/32 = 3125 exactly.
// ---------------------------------------------------------------------------
#define QKV_RPW 8
__global__ __launch_bounds__(256) void qkv_kernel(
    const u16* __restrict__ xraw, const float* __restrict__ cw,
    float* __restrict__ Q, float* __restrict__ K, float* __restrict__ V)
{
    bool isf32 = detect_f32(xraw);
    const int wid  = threadIdx.x >> 6;
    const int lane = threadIdx.x & 63;
    const int base = (blockIdx.x * 4 + wid) * QKV_RPW;
    const int c    = lane;

    float xr[QKV_RPW];
    if (isf32) {
        const float* xp = (const float*)xraw;
#pragma unroll
        for (int r = 0; r < QKV_RPW; r++)
            xr[r] = xp[(size_t)(base + r) * 64 + lane];
    } else {
#pragma unroll
        for (int r = 0; r < QKV_RPW; r++)
            xr[r] = us2f(xraw[(size_t)(base + r) * 64 + lane]);
    }

    float aq[QKV_RPW], ak[QKV_RPW], av[QKV_RPW];
    const float bqc = cw[OFF_BQ + c], bkc = cw[OFF_BK + c], bvc = cw[OFF_BV + c];
#pragma unroll
    for (int r = 0; r < QKV_RPW; r++) { aq[r] = bqc; ak[r] = bkc; av[r] = bvc; }

#pragma unroll 16
    for (int k = 0; k < 64; k++) {
        float wqk = cw[OFF_WQ + k * 64 + c];
        float wkk = cw[OFF_WK + k * 64 + c];
        float wvk = cw[OFF_WV + k * 64 + c];
#pragma unroll
        for (int r = 0; r < QKV_RPW; r++) {
            float xv = __shfl(xr[r], k, 64);
            aq[r] = fmaf(xv, wqk, aq[r]);
            ak[r] = fmaf(xv, wkk, ak[r]);
            av[r] = fmaf(xv, wvk, av[r]);
        }
    }
#pragma unroll
    for (int r = 0; r < QKV_RPW; r++) {
        Q[(size_t)(base + r) * 64 + c] = aq[r];
        K[(size_t)(base + r) * 64 + c] = ak[r];
        V[(size_t)(base + r) * 64 + c] = av[r];
    }
}

// ---------------------------------------------------------------------------
// K2: fused attention. 256-thread block = 4 waves = 4 points (one wave per
// point, pt = tid>>6) to escape the 16-workgroup/CU cap. Lane = channel c.
// Same trusted per-wave logic as the passing round-4 kernel, with two
// mechanical changes: pv kept in registers (was pvbuf LDS), and stage 2
// reads wvbuf as float4 (stride 68). Grid = 25000 exactly.
// ---------------------------------------------------------------------------
__global__ __launch_bounds__(256) void attn_kernel(
    const u16* __restrict__ P, const int* __restrict__ IDX,
    const u16* __restrict__ xprobe, const float* __restrict__ cw,
    const float* __restrict__ Q, const float* __restrict__ K,
    const float* __restrict__ V, void* __restrict__ OUT)
{
    __shared__ __align__(16) float wvbuf[4][NSAMP * 68];  // relu(bn1(w)), stride 68
    __shared__ __align__(16) float tbbuf[4][NSAMP * 8];   // relu(bn2(.@Wa+ba))
    __shared__ __align__(16) float w2buf[4][NSAMP * 8];   // logits -> softmax wts

    bool isf32 = detect_f32(xprobe);

    const int pt = threadIdx.x >> 6;
    const int c  = threadIdx.x & 63;
    const int i  = blockIdx.x * 4 + pt;        // grid*4 == N_PTS exactly
    const float rs = 1.0f / sqrtf(1.0f + 1e-5f);

    // per-lane channel constants
    const float wp2c0 = cw[OFF_WP2 + 0 * 64 + c];
    const float wp2c1 = cw[OFF_WP2 + 1 * 64 + c];
    const float wp2c2 = cw[OFF_WP2 + 2 * 64 + c];
    const float bp2c  = cw[OFF_BP2 + c];
    const float g1c   = cw[OFF_G1  + c] * rs;
    const float bb1c  = cw[OFF_BB1 + c];
    float wp1f[9], bp1f[3];
#pragma unroll
    for (int d = 0; d < 3; d++) {
        float gd = cw[OFF_GP + d] * rs;
#pragma unroll
        for (int e = 0; e < 3; e++) wp1f[e * 3 + d] = cw[OFF_WP1 + e * 3 + d] * gd;
        bp1f[d] = cw[OFF_BP1 + d] * gd + cw[OFF_BP + d];
    }

    const float* Pf = (const float*)P;
    float pi0, pi1, pi2;
    if (isf32) { pi0 = Pf[i*3+0]; pi1 = Pf[i*3+1]; pi2 = Pf[i*3+2]; }
    else       { pi0 = us2f(P[i*3+0]); pi1 = us2f(P[i*3+1]); pi2 = us2f(P[i*3+2]); }

    const float qq = Q[(size_t)i * 64 + c];
    float pv[NSAMP];

    // ---- stage 1: per-(n,c) relation input into LDS; v+pe kept in regs ----
#pragma unroll
    for (int n = 0; n < NSAMP; n++) {
        const int j = IDX[i * NSAMP + n];
        float pr0, pr1, pr2;
        if (isf32) {
            pr0 = Pf[j*3+0] - pi0; pr1 = Pf[j*3+1] - pi1; pr2 = Pf[j*3+2] - pi2;
        } else {
            pr0 = us2f(P[j*3+0]) - pi0; pr1 = us2f(P[j*3+1]) - pi1; pr2 = us2f(P[j*3+2]) - pi2;
        }
        float h0 = fmaxf(fmaf(pr2, wp1f[6], fmaf(pr1, wp1f[3], fmaf(pr0, wp1f[0], bp1f[0]))), 0.0f);
        float h1 = fmaxf(fmaf(pr2, wp1f[7], fmaf(pr1, wp1f[4], fmaf(pr0, wp1f[1], bp1f[1]))), 0.0f);
        float h2 = fmaxf(fmaf(pr2, wp1f[8], fmaf(pr1, wp1f[5], fmaf(pr0, wp1f[2], bp1f[2]))), 0.0f);
        float pe = fmaf(h2, wp2c2, fmaf(h1, wp2c1, fmaf(h0, wp2c0, bp2c)));
        float kk = K[(size_t)j * 64 + c];
        float vv = V[(size_t)j * 64 + c];
        wvbuf[pt][n * 68 + c] = fmaxf(fmaf(kk - qq + pe, g1c, bb1c), 0.0f);
        pv[n] = vv + pe;
    }
    __syncthreads();

    // ---- stage 2: a[n][s] = ba[s] + sum_c wv[n][c]*Wa[c][s]; tb = relu(bn2) ----
#pragma unroll
    for (int rep = 0; rep < 2; rep++) {
        int T = c + rep * 64;
        int n = T >> 3, s = T & 7;
        float a = cw[OFF_BA + s];
#pragma unroll
        for (int c4 = 0; c4 < 16; c4++) {
            float4 w4 = *((const float4*)&wvbuf[pt][n * 68 + c4 * 4]);
            a = fmaf(w4.x, cw[OFF_WA + (c4 * 4 + 0) * 8 + s], a);
            a = fmaf(w4.y, cw[OFF_WA + (c4 * 4 + 1) * 8 + s], a);
            a = fmaf(w4.z, cw[OFF_WA + (c4 * 4 + 2) * 8 + s], a);
            a = fmaf(w4.w, cw[OFF_WA + (c4 * 4 + 3) * 8 + s], a);
        }
        tbbuf[pt][n * 8 + s] = fmaxf(fmaf(a, cw[OFF_G2 + s] * rs, cw[OFF_BB2 + s]), 0.0f);
    }
    __syncthreads();

    // ---- stage 3: logits w2[n][t] = bw[t] + sum_s tb[n][s]*Wb[s][t] ----
#pragma unroll
    for (int rep = 0; rep < 2; rep++) {
        int T = c + rep * 64;
        int n = T >> 3, t = T & 7;
        float w2 = cw[OFF_BW + t];
#pragma unroll
        for (int s = 0; s < 8; s++)
            w2 = fmaf(tbbuf[pt][n * 8 + s], cw[OFF_WB + s * 8 + t], w2);
        w2buf[pt][n * 8 + t] = w2;
    }
    __syncthreads();

    // ---- stage 4: softmax over neighbors per attention channel t (lanes 0..7) ----
    if (c < 8) {
        float mx = -1e30f;
#pragma unroll
        for (int n = 0; n < NSAMP; n++) mx = fmaxf(mx, w2buf[pt][n * 8 + c]);
        float sm = 0.0f;
        float e[NSAMP];
#pragma unroll
        for (int n = 0; n < NSAMP; n++) { e[n] = __expf(w2buf[pt][n * 8 + c] - mx); sm += e[n]; }
        float inv = 1.0f / sm;
#pragma unroll
        for (int n = 0; n < NSAMP; n++) w2buf[pt][n * 8 + c] = e[n] * inv;
    }
    __syncthreads();

    // ---- stage 5: out[c] = sum_n pv[n] * w[n][c&7] ----
    const int t = c & 7;
    float o = 0.0f;
#pragma unroll
    for (int n = 0; n < NSAMP; n++)
        o = fmaf(pv[n], w2buf[pt][n * 8 + t], o);
    if (isf32) ((float*)OUT)[(size_t)i * 64 + c] = o;
    else       ((__hip_bfloat16*)OUT)[(size_t)i * 64 + c] = __float2bfloat16(o);
}

// ---------------------------------------------------------------------------
extern "C" void kernel_launch(void* const* d_in, const int* in_sizes, int n_in,
                              void* d_out, int out_size, void* d_ws, size_t ws_size,
                              hipStream_t stream)
{
    const u16* p   = (const u16*)d_in[0];
    const u16* x   = (const u16*)d_in[1];
    const int* idx = (const int*)d_in[2];

    // workspace layout (76.9 MB — proven safe)
    float* cw = (float*)d_ws;                 // 64 KB
    float* Q  = cw + CW_PAD;                  // N*64 f32 = 25.6 MB
    float* K  = Q + (size_t)N_PTS * 64;       // 25.6 MB
    float* V  = K + (size_t)N_PTS * 64;       // 25.6 MB

    convert_kernel<<<8, 256, 0, stream>>>(
        x,
        d_in[3],  d_in[4],  d_in[5],  d_in[6],  d_in[7],  d_in[8],
        d_in[9],  d_in[10], d_in[11], d_in[12], d_in[13], d_in[14],
        d_in[15], d_in[16], d_in[17], d_in[18], d_in[19], d_in[20],
        d_in[21], d_in[22], cw);
    qkv_kernel<<<3125, 256, 0, stream>>>(x, cw, Q, K, V);     // 3125*32 = 100000
    attn_kernel<<<N_PTS / 4, 256, 0, stream>>>(p, idx, x, cw, Q, K, V, d_out);
}

// Round 2
// 416.571 us; speedup vs baseline: 1.3680x; 1.3680x over previous
//
#include <hip/hip_runtime.h>
#include <hip/hip_bf16.h>

typedef unsigned int u32;
typedef unsigned short u16;

#define N_PTS 100000
#define NSAMP 16

__device__ __forceinline__ float lo2f(u32 u){ return __uint_as_float(u << 16); }
__device__ __forceinline__ float hi2f(u32 u){ return __uint_as_float(u & 0xffff0000u); }
__device__ __forceinline__ float us2f(u16 u){ return __uint_as_float(((u32)u) << 16); }

// round-to-nearest-even f32 -> bf16 bits (finite values only)
__device__ __forceinline__ u16 f2bf(float f) {
    u32 u = __float_as_uint(f);
    return (u16)((u + 0x7fffu + ((u >> 16) & 1u)) >> 16);
}
__device__ __forceinline__ u32 pack2(float k, float v) {
    return (u32)f2bf(k) | ((u32)f2bf(v) << 16);
}

// Runtime input-dtype probe. Reads only EVEN u16 indices (= low halves if the
// buffer is fp32). fp32: low halves decode as bf16 with random exponents ->
// ~46% exceed 1024 in magnitude. bf16 N(0,1): zero hits.
// Must be called by ALL threads of the block (contains a barrier).
__device__ __forceinline__ bool detect_f32(const u16* __restrict__ xprobe) {
    float f = us2f(xprobe[(threadIdx.x & 63) * 2]);
    int cnt = __syncthreads_count(fabsf(f) > 1024.0f ? 1 : 0);
    return cnt >= 8;
}

// canonical fp32 weight-block offsets (floats, each 16B-aligned)
#define OFF_WQ   0
#define OFF_BQ   4096
#define OFF_WK   4160
#define OFF_BK   8256
#define OFF_WV   8320
#define OFF_BV   12416
#define OFF_WP1  12480
#define OFF_BP1  12492
#define OFF_GP   12496
#define OFF_BP   12500
#define OFF_WP2  12504
#define OFF_BP2  12696
#define OFF_G1   12760
#define OFF_BB1  12824
#define OFF_WA   12888
#define OFF_BA   13400
#define OFF_G2   13408
#define OFF_BB2  13416
#define OFF_WB   13424
#define OFF_BW   13488
#define CW_PAD   16384   /* pad region to 64 KB of floats */

// ---------------------------------------------------------------------------
// K0: canonicalize all small weight arrays to fp32 (handles bf16 or fp32 src)
// ---------------------------------------------------------------------------
__global__ __launch_bounds__(256) void convert_kernel(
    const u16* __restrict__ xprobe,
    const void* s0,  const void* s1,  const void* s2,  const void* s3,
    const void* s4,  const void* s5,  const void* s6,  const void* s7,
    const void* s8,  const void* s9,  const void* s10, const void* s11,
    const void* s12, const void* s13, const void* s14, const void* s15,
    const void* s16, const void* s17, const void* s18, const void* s19,
    float* __restrict__ cw)
{
    bool isf32 = detect_f32(xprobe);
    const void* srcs[20] = {s0,s1,s2,s3,s4,s5,s6,s7,s8,s9,s10,s11,s12,s13,s14,s15,s16,s17,s18,s19};
    const int sizes[20] = {4096,64,4096,64,4096,64,9,3,3,3,192,64,64,64,512,8,8,8,64,8};
    const int offs[20]  = {OFF_WQ,OFF_BQ,OFF_WK,OFF_BK,OFF_WV,OFF_BV,OFF_WP1,OFF_BP1,OFF_GP,OFF_BP,
                           OFF_WP2,OFF_BP2,OFF_G1,OFF_BB1,OFF_WA,OFF_BA,OFF_G2,OFF_BB2,OFF_WB,OFF_BW};
    int tid = threadIdx.x + blockIdx.x * 256;
    int stride = gridDim.x * 256;
    for (int a = 0; a < 20; a++) {
        const void* s = srcs[a];
        for (int k = tid; k < sizes[a]; k += stride)
            cw[offs[a] + k] = isf32 ? ((const float*)s)[k] : us2f(((const u16*)s)[k]);
    }
}

// ---------------------------------------------------------------------------
// K1: Q = x@Wq+bq ; K,V packed bf16x2 per channel.  (register-blocked)
// Each wave handles 8 rows; lane c owns output column c of all 8 rows.
// Block = 256 = 4 waves = 32 rows; grid = 100000/32 = 3125 exactly.
// KV[row][c] = {bf16(K) | bf16(V)<<16} -> attn gathers one dword per
// neighbor-channel instead of two fp32 loads (halves gather bytes & instrs).
// ---------------------------------------------------------------------------
#define QKV_RPW 8
__global__ __launch_bounds__(256) void qkv_kernel(
    const u16* __restrict__ xraw, const float* __restrict__ cw,
    float* __restrict__ Q, u32* __restrict__ KV)
{
    bool isf32 = detect_f32(xraw);
    const int wid  = threadIdx.x >> 6;
    const int lane = threadIdx.x & 63;
    const int base = (blockIdx.x * 4 + wid) * QKV_RPW;
    const int c    = lane;

    float xr[QKV_RPW];
    if (isf32) {
        const float* xp = (const float*)xraw;
#pragma unroll
        for (int r = 0; r < QKV_RPW; r++)
            xr[r] = xp[(size_t)(base + r) * 64 + lane];
    } else {
#pragma unroll
        for (int r = 0; r < QKV_RPW; r++)
            xr[r] = us2f(xraw[(size_t)(base + r) * 64 + lane]);
    }

    float aq[QKV_RPW], ak[QKV_RPW], av[QKV_RPW];
    const float bqc = cw[OFF_BQ + c], bkc = cw[OFF_BK + c], bvc = cw[OFF_BV + c];
#pragma unroll
    for (int r = 0; r < QKV_RPW; r++) { aq[r] = bqc; ak[r] = bkc; av[r] = bvc; }

#pragma unroll 16
    for (int k = 0; k < 64; k++) {
        float wqk = cw[OFF_WQ + k * 64 + c];
        float wkk = cw[OFF_WK + k * 64 + c];
        float wvk = cw[OFF_WV + k * 64 + c];
#pragma unroll
        for (int r = 0; r < QKV_RPW; r++) {
            float xv = __shfl(xr[r], k, 64);
            aq[r] = fmaf(xv, wqk, aq[r]);
            ak[r] = fmaf(xv, wkk, ak[r]);
            av[r] = fmaf(xv, wvk, av[r]);
        }
    }
#pragma unroll
    for (int r = 0; r < QKV_RPW; r++) {
        Q[(size_t)(base + r) * 64 + c]  = aq[r];
        KV[(size_t)(base + r) * 64 + c] = pack2(ak[r], av[r]);
    }
}

// ---------------------------------------------------------------------------
// K2: fused attention. 256-thread block = 4 waves = 4 points (one wave per
// point, pt = tid>>6). Lane = channel c. Grid = 25000 exactly.
// Stage-1 load restructure vs round-0:
//   - IDX: one lane-distributed load (lane n<16 holds j_n), was 16 loads
//   - KV : 16 explicitly prefetched packed-dword gathers held in registers
//          (forces all 16 in flight -> memory-level parallelism)
//   - P  : one lane-distributed load (lane l<48 holds P[j_{l/3}][l%3]),
//          redistributed via __shfl, was 48 broadcast loads
// ---------------------------------------------------------------------------
__global__ __launch_bounds__(256) void attn_kernel(
    const u16* __restrict__ P, const int* __restrict__ IDX,
    const u16* __restrict__ xprobe, const float* __restrict__ cw,
    const float* __restrict__ Q, const u32* __restrict__ KV,
    void* __restrict__ OUT)
{
    __shared__ __align__(16) float wvbuf[4][NSAMP * 68];  // relu(bn1(w)), stride 68
    __shared__ __align__(16) float tbbuf[4][NSAMP * 8];   // relu(bn2(.@Wa+ba))
    __shared__ __align__(16) float w2buf[4][NSAMP * 8];   // logits -> softmax wts

    bool isf32 = detect_f32(xprobe);

    const int pt = threadIdx.x >> 6;
    const int c  = threadIdx.x & 63;
    const int i  = blockIdx.x * 4 + pt;        // grid*4 == N_PTS exactly
    const float rs = 1.0f / sqrtf(1.0f + 1e-5f);

    // ---- issue the index load, then all 16 gathers, before anything else ----
    const int jv = IDX[(size_t)i * NSAMP + (c & 15)];   // lane n<16: j_n

    u32 kvw[NSAMP];
#pragma unroll
    for (int n = 0; n < NSAMP; n++) {
        int j = __shfl(jv, n, 64);            // wave-uniform -> saddr form
        kvw[n] = KV[(size_t)j * 64 + c];
    }

    // distributed P gather: lane l (l<48) holds P[j_{l/3}][l%3]
    const int n_p = c / 3;
    const int d_p = c - n_p * 3;
    const int j_p = __shfl(jv, n_p & 15, 64);
    const float* Pf = (const float*)P;
    float pl;
    if (isf32) pl = Pf[(size_t)j_p * 3 + d_p];
    else       pl = us2f(P[(size_t)j_p * 3 + d_p]);

    const float qq = Q[(size_t)i * 64 + c];

    float pi0, pi1, pi2;
    if (isf32) { pi0 = Pf[i*3+0]; pi1 = Pf[i*3+1]; pi2 = Pf[i*3+2]; }
    else       { pi0 = us2f(P[i*3+0]); pi1 = us2f(P[i*3+1]); pi2 = us2f(P[i*3+2]); }

    // per-lane channel constants (L1-hot)
    const float wp2c0 = cw[OFF_WP2 + 0 * 64 + c];
    const float wp2c1 = cw[OFF_WP2 + 1 * 64 + c];
    const float wp2c2 = cw[OFF_WP2 + 2 * 64 + c];
    const float bp2c  = cw[OFF_BP2 + c];
    const float g1c   = cw[OFF_G1  + c] * rs;
    const float bb1c  = cw[OFF_BB1 + c];
    float wp1f[9], bp1f[3];
#pragma unroll
    for (int d = 0; d < 3; d++) {
        float gd = cw[OFF_GP + d] * rs;
#pragma unroll
        for (int e = 0; e < 3; e++) wp1f[e * 3 + d] = cw[OFF_WP1 + e * 3 + d] * gd;
        bp1f[d] = cw[OFF_BP1 + d] * gd + cw[OFF_BP + d];
    }

    float pv[NSAMP];

    // ---- stage 1: per-(n,c) relation input into LDS; v+pe kept in regs ----
#pragma unroll
    for (int n = 0; n < NSAMP; n++) {
        float pr0 = __shfl(pl, n * 3 + 0, 64) - pi0;
        float pr1 = __shfl(pl, n * 3 + 1, 64) - pi1;
        float pr2 = __shfl(pl, n * 3 + 2, 64) - pi2;
        float h0 = fmaxf(fmaf(pr2, wp1f[6], fmaf(pr1, wp1f[3], fmaf(pr0, wp1f[0], bp1f[0]))), 0.0f);
        float h1 = fmaxf(fmaf(pr2, wp1f[7], fmaf(pr1, wp1f[4], fmaf(pr0, wp1f[1], bp1f[1]))), 0.0f);
        float h2 = fmaxf(fmaf(pr2, wp1f[8], fmaf(pr1, wp1f[5], fmaf(pr0, wp1f[2], bp1f[2]))), 0.0f);
        float pe = fmaf(h2, wp2c2, fmaf(h1, wp2c1, fmaf(h0, wp2c0, bp2c)));
        float kk = lo2f(kvw[n]);
        float vv = hi2f(kvw[n]);
        wvbuf[pt][n * 68 + c] = fmaxf(fmaf(kk - qq + pe, g1c, bb1c), 0.0f);
        pv[n] = vv + pe;
    }
    __syncthreads();

    // ---- stage 2: a[n][s] = ba[s] + sum_c wv[n][c]*Wa[c][s]; tb = relu(bn2) ----
#pragma unroll
    for (int rep = 0; rep < 2; rep++) {
        int T = c + rep * 64;
        int n = T >> 3, s = T & 7;
        float a = cw[OFF_BA + s];
#pragma unroll
        for (int c4 = 0; c4 < 16; c4++) {
            float4 w4 = *((const float4*)&wvbuf[pt][n * 68 + c4 * 4]);
            a = fmaf(w4.x, cw[OFF_WA + (c4 * 4 + 0) * 8 + s], a);
            a = fmaf(w4.y, cw[OFF_WA + (c4 * 4 + 1) * 8 + s], a);
            a = fmaf(w4.z, cw[OFF_WA + (c4 * 4 + 2) * 8 + s], a);
            a = fmaf(w4.w, cw[OFF_WA + (c4 * 4 + 3) * 8 + s], a);
        }
        tbbuf[pt][n * 8 + s] = fmaxf(fmaf(a, cw[OFF_G2 + s] * rs, cw[OFF_BB2 + s]), 0.0f);
    }
    __syncthreads();

    // ---- stage 3: logits w2[n][t] = bw[t] + sum_s tb[n][s]*Wb[s][t] ----
#pragma unroll
    for (int rep = 0; rep < 2; rep++) {
        int T = c + rep * 64;
        int n = T >> 3, t = T & 7;
        float w2 = cw[OFF_BW + t];
#pragma unroll
        for (int s = 0; s < 8; s++)
            w2 = fmaf(tbbuf[pt][n * 8 + s], cw[OFF_WB + s * 8 + t], w2);
        w2buf[pt][n * 8 + t] = w2;
    }
    __syncthreads();

    // ---- stage 4: softmax over neighbors per attention channel t (lanes 0..7) ----
    if (c < 8) {
        float mx = -1e30f;
#pragma unroll
        for (int n = 0; n < NSAMP; n++) mx = fmaxf(mx, w2buf[pt][n * 8 + c]);
        float sm = 0.0f;
        float e[NSAMP];
#pragma unroll
        for (int n = 0; n < NSAMP; n++) { e[n] = __expf(w2buf[pt][n * 8 + c] - mx); sm += e[n]; }
        float inv = 1.0f / sm;
#pragma unroll
        for (int n = 0; n < NSAMP; n++) w2buf[pt][n * 8 + c] = e[n] * inv;
    }
    __syncthreads();

    // ---- stage 5: out[c] = sum_n pv[n] * w[n][c&7] ----
    const int t = c & 7;
    float o = 0.0f;
#pragma unroll
    for (int n = 0; n < NSAMP; n++)
        o = fmaf(pv[n], w2buf[pt][n * 8 + t], o);
    if (isf32) ((float*)OUT)[(size_t)i * 64 + c] = o;
    else       ((__hip_bfloat16*)OUT)[(size_t)i * 64 + c] = __float2bfloat16(o);
}

// ---------------------------------------------------------------------------
extern "C" void kernel_launch(void* const* d_in, const int* in_sizes, int n_in,
                              void* d_out, int out_size, void* d_ws, size_t ws_size,
                              hipStream_t stream)
{
    const u16* p   = (const u16*)d_in[0];
    const u16* x   = (const u16*)d_in[1];
    const int* idx = (const int*)d_in[2];

    // workspace layout: cw 64KB + Q 25.6MB + KV 25.6MB = 51.3 MB (< proven 76.9)
    float* cw = (float*)d_ws;                 // 64 KB
    float* Q  = cw + CW_PAD;                  // N*64 f32 = 25.6 MB
    u32*   KV = (u32*)(Q + (size_t)N_PTS * 64); // N*64 u32 = 25.6 MB

    convert_kernel<<<8, 256, 0, stream>>>(
        x,
        d_in[3],  d_in[4],  d_in[5],  d_in[6],  d_in[7],  d_in[8],
        d_in[9],  d_in[10], d_in[11], d_in[12], d_in[13], d_in[14],
        d_in[15], d_in[16], d_in[17], d_in[18], d_in[19], d_in[20],
        d_in[21], d_in[22], cw);
    qkv_kernel<<<3125, 256, 0, stream>>>(x, cw, Q, KV);       // 3125*32 = 100000
    attn_kernel<<<N_PTS / 4, 256, 0, stream>>>(p, idx, x, cw, Q, KV, d_out);
}

// Round 3
// 367.134 us; speedup vs baseline: 1.5522x; 1.1347x over previous
//
#include <hip/hip_runtime.h>
#include <hip/hip_bf16.h>

typedef unsigned int u32;
typedef unsigned short u16;
typedef __attribute__((ext_vector_type(8))) short short8;   // 8 bf16 (4 VGPRs)
typedef __attribute__((ext_vector_type(4))) float f32x4;    // MFMA C/D

#define N_PTS 100000
#define NSAMP 16

__device__ __forceinline__ float lo2f(u32 u){ return __uint_as_float(u << 16); }
__device__ __forceinline__ float hi2f(u32 u){ return __uint_as_float(u & 0xffff0000u); }
__device__ __forceinline__ float us2f(u16 u){ return __uint_as_float(((u32)u) << 16); }

// round-to-nearest-even f32 -> bf16 bits (finite values only)
__device__ __forceinline__ u16 f2bf(float f) {
    u32 u = __float_as_uint(f);
    return (u16)((u + 0x7fffu + ((u >> 16) & 1u)) >> 16);
}
__device__ __forceinline__ u32 pack2(float k, float v) {
    return (u32)f2bf(k) | ((u32)f2bf(v) << 16);
}

// Runtime input-dtype probe (must be called by ALL threads of the block).
__device__ __forceinline__ bool detect_f32(const u16* __restrict__ xprobe) {
    float f = us2f(xprobe[(threadIdx.x & 63) * 2]);
    int cnt = __syncthreads_count(fabsf(f) > 1024.0f ? 1 : 0);
    return cnt >= 8;
}

// canonical fp32 weight-block offsets (floats, each 16B-aligned)
#define OFF_WQ   0
#define OFF_BQ   4096
#define OFF_WK   4160
#define OFF_BK   8256
#define OFF_WV   8320
#define OFF_BV   12416
#define OFF_WP1  12480
#define OFF_BP1  12492
#define OFF_GP   12496
#define OFF_BP   12500
#define OFF_WP2  12504
#define OFF_BP2  12696
#define OFF_G1   12760
#define OFF_BB1  12824
#define OFF_WA   12888
#define OFF_BA   13400
#define OFF_G2   13408
#define OFF_BB2  13416
#define OFF_WB   13424
#define OFF_BW   13488
#define CW_PAD   16384   /* pad region to 64 KB of floats */

// ---------------------------------------------------------------------------
// K0: canonicalize all small weight arrays to fp32 (handles bf16 or fp32 src)
// ---------------------------------------------------------------------------
__global__ __launch_bounds__(256) void convert_kernel(
    const u16* __restrict__ xprobe,
    const void* s0,  const void* s1,  const void* s2,  const void* s3,
    const void* s4,  const void* s5,  const void* s6,  const void* s7,
    const void* s8,  const void* s9,  const void* s10, const void* s11,
    const void* s12, const void* s13, const void* s14, const void* s15,
    const void* s16, const void* s17, const void* s18, const void* s19,
    float* __restrict__ cw)
{
    bool isf32 = detect_f32(xprobe);
    const void* srcs[20] = {s0,s1,s2,s3,s4,s5,s6,s7,s8,s9,s10,s11,s12,s13,s14,s15,s16,s17,s18,s19};
    const int sizes[20] = {4096,64,4096,64,4096,64,9,3,3,3,192,64,64,64,512,8,8,8,64,8};
    const int offs[20]  = {OFF_WQ,OFF_BQ,OFF_WK,OFF_BK,OFF_WV,OFF_BV,OFF_WP1,OFF_BP1,OFF_GP,OFF_BP,
                           OFF_WP2,OFF_BP2,OFF_G1,OFF_BB1,OFF_WA,OFF_BA,OFF_G2,OFF_BB2,OFF_WB,OFF_BW};
    int tid = threadIdx.x + blockIdx.x * 256;
    int stride = gridDim.x * 256;
    for (int a = 0; a < 20; a++) {
        const void* s = srcs[a];
        for (int k = tid; k < sizes[a]; k += stride)
            cw[offs[a] + k] = isf32 ? ((const float*)s)[k] : us2f(((const u16*)s)[k]);
    }
}

// ---------------------------------------------------------------------------
// K1: MFMA QKV projection.  x[100000,64] @ {Wq|Wk|Wv}[64,192] + bias.
// mfma_f32_16x16x32_bf16, hi/lo-split weights for ~fp32 accuracy:
//   bf16 input :  x@Wh + x@Wl            (12 mfma / M-tile / wave)
//   fp32 input :  xh@Wh + xh@Wl + xl@Wh  (18 mfma / M-tile / wave)
// Wave w owns n-tiles {Q_w, K_w, V_w}; B-frags live in registers (48 VGPR).
// A k-mapping k = (lane>>4)*8 + j is used for BOTH A and B, so any internal
// hardware k-permutation cancels. C/D: col=lane&15, row=(lane>>4)*4+reg
// (m89-verified). K,V pack to bf16x2 KV dwords (attn gathers 1 dword/nbr).
// Grid 1250 x 5 M-tiles = 6250 tiles * 16 rows = 100000 exactly.
// ---------------------------------------------------------------------------
#define QKV_TPB 5
__global__ __launch_bounds__(256) void qkv_mfma_kernel(
    const u16* __restrict__ xraw, const float* __restrict__ cw,
    float* __restrict__ Q, u32* __restrict__ KV)
{
    bool isf32 = detect_f32(xraw);
    const int w   = threadIdx.x >> 6;   // wave id = n-tile id within Q/K/V
    const int l   = threadIdx.x & 63;
    const int col = l & 15;             // N-col (B/D) or M-row (A) within tile
    const int g   = l >> 4;             // k-group

    // ---- build B fragments (weights) in registers: hi/lo bf16 planes ----
    short8 bh[3][2], bl[3][2];
    const int moff[3] = {OFF_WQ, OFF_WK, OFF_WV};
#pragma unroll
    for (int m = 0; m < 3; m++)
#pragma unroll
        for (int kh = 0; kh < 2; kh++)
#pragma unroll
            for (int j = 0; j < 8; j++) {
                float wv = cw[moff[m] + (kh * 32 + g * 8 + j) * 64 + w * 16 + col];
                u16 hb = f2bf(wv);
                bh[m][kh][j] = (short)hb;
                bl[m][kh][j] = (short)f2bf(wv - us2f(hb));
            }
    const float bqc = cw[OFF_BQ + w * 16 + col];
    const float bkc = cw[OFF_BK + w * 16 + col];
    const float bvc = cw[OFF_BV + w * 16 + col];

    for (int it = 0; it < QKV_TPB; it++) {
        const int M0 = (blockIdx.x * QKV_TPB + it) * 16;

        f32x4 aQ = {bqc, bqc, bqc, bqc};
        f32x4 aK = {bkc, bkc, bkc, bkc};
        f32x4 aV = {bvc, bvc, bvc, bvc};

        short8 ah[2], al[2];
        if (isf32) {
            const float4* xf = (const float4*)xraw;
#pragma unroll
            for (int kh = 0; kh < 2; kh++) {
                float4 f0 = xf[(size_t)(M0 + col) * 16 + kh * 8 + g * 2];
                float4 f1 = xf[(size_t)(M0 + col) * 16 + kh * 8 + g * 2 + 1];
                float ff[8] = {f0.x, f0.y, f0.z, f0.w, f1.x, f1.y, f1.z, f1.w};
#pragma unroll
                for (int j = 0; j < 8; j++) {
                    u16 hb = f2bf(ff[j]);
                    ah[kh][j] = (short)hb;
                    al[kh][j] = (short)f2bf(ff[j] - us2f(hb));
                }
            }
        } else {
            const short8* xb = (const short8*)xraw;
#pragma unroll
            for (int kh = 0; kh < 2; kh++)
                ah[kh] = xb[(size_t)(M0 + col) * 8 + kh * 4 + g];
        }

#pragma unroll
        for (int kh = 0; kh < 2; kh++) {
            aQ = __builtin_amdgcn_mfma_f32_16x16x32_bf16(ah[kh], bh[0][kh], aQ, 0, 0, 0);
            aK = __builtin_amdgcn_mfma_f32_16x16x32_bf16(ah[kh], bh[1][kh], aK, 0, 0, 0);
            aV = __builtin_amdgcn_mfma_f32_16x16x32_bf16(ah[kh], bh[2][kh], aV, 0, 0, 0);
            aQ = __builtin_amdgcn_mfma_f32_16x16x32_bf16(ah[kh], bl[0][kh], aQ, 0, 0, 0);
            aK = __builtin_amdgcn_mfma_f32_16x16x32_bf16(ah[kh], bl[1][kh], aK, 0, 0, 0);
            aV = __builtin_amdgcn_mfma_f32_16x16x32_bf16(ah[kh], bl[2][kh], aV, 0, 0, 0);
            if (isf32) {
                aQ = __builtin_amdgcn_mfma_f32_16x16x32_bf16(al[kh], bh[0][kh], aQ, 0, 0, 0);
                aK = __builtin_amdgcn_mfma_f32_16x16x32_bf16(al[kh], bh[1][kh], aK, 0, 0, 0);
                aV = __builtin_amdgcn_mfma_f32_16x16x32_bf16(al[kh], bh[2][kh], aV, 0, 0, 0);
            }
        }

        // ---- epilogue: D col=lane&15, row=(lane>>4)*4+reg ----
#pragma unroll
        for (int r = 0; r < 4; r++) {
            int row = M0 + g * 4 + r;
            Q [(size_t)row * 64 + w * 16 + col] = aQ[r];
            KV[(size_t)row * 64 + w * 16 + col] = pack2(aK[r], aV[r]);
        }
    }
}

// ---------------------------------------------------------------------------
// K2: fused attention (unchanged from round 2 — 247 us, passing).
// ---------------------------------------------------------------------------
__global__ __launch_bounds__(256) void attn_kernel(
    const u16* __restrict__ P, const int* __restrict__ IDX,
    const u16* __restrict__ xprobe, const float* __restrict__ cw,
    const float* __restrict__ Q, const u32* __restrict__ KV,
    void* __restrict__ OUT)
{
    __shared__ __align__(16) float wvbuf[4][NSAMP * 68];  // relu(bn1(w)), stride 68
    __shared__ __align__(16) float tbbuf[4][NSAMP * 8];   // relu(bn2(.@Wa+ba))
    __shared__ __align__(16) float w2buf[4][NSAMP * 8];   // logits -> softmax wts

    bool isf32 = detect_f32(xprobe);

    const int pt = threadIdx.x >> 6;
    const int c  = threadIdx.x & 63;
    const int i  = blockIdx.x * 4 + pt;        // grid*4 == N_PTS exactly
    const float rs = 1.0f / sqrtf(1.0f + 1e-5f);

    // ---- issue the index load, then all 16 gathers, before anything else ----
    const int jv = IDX[(size_t)i * NSAMP + (c & 15)];   // lane n<16: j_n

    u32 kvw[NSAMP];
#pragma unroll
    for (int n = 0; n < NSAMP; n++) {
        int j = __shfl(jv, n, 64);            // wave-uniform -> saddr form
        kvw[n] = KV[(size_t)j * 64 + c];
    }

    // distributed P gather: lane l (l<48) holds P[j_{l/3}][l%3]
    const int n_p = c / 3;
    const int d_p = c - n_p * 3;
    const int j_p = __shfl(jv, n_p & 15, 64);
    const float* Pf = (const float*)P;
    float pl;
    if (isf32) pl = Pf[(size_t)j_p * 3 + d_p];
    else       pl = us2f(P[(size_t)j_p * 3 + d_p]);

    const float qq = Q[(size_t)i * 64 + c];

    float pi0, pi1, pi2;
    if (isf32) { pi0 = Pf[i*3+0]; pi1 = Pf[i*3+1]; pi2 = Pf[i*3+2]; }
    else       { pi0 = us2f(P[i*3+0]); pi1 = us2f(P[i*3+1]); pi2 = us2f(P[i*3+2]); }

    // per-lane channel constants (L1-hot)
    const float wp2c0 = cw[OFF_WP2 + 0 * 64 + c];
    const float wp2c1 = cw[OFF_WP2 + 1 * 64 + c];
    const float wp2c2 = cw[OFF_WP2 + 2 * 64 + c];
    const float bp2c  = cw[OFF_BP2 + c];
    const float g1c   = cw[OFF_G1  + c] * rs;
    const float bb1c  = cw[OFF_BB1 + c];
    float wp1f[9], bp1f[3];
#pragma unroll
    for (int d = 0; d < 3; d++) {
        float gd = cw[OFF_GP + d] * rs;
#pragma unroll
        for (int e = 0; e < 3; e++) wp1f[e * 3 + d] = cw[OFF_WP1 + e * 3 + d] * gd;
        bp1f[d] = cw[OFF_BP1 + d] * gd + cw[OFF_BP + d];
    }

    float pv[NSAMP];

    // ---- stage 1: per-(n,c) relation input into LDS; v+pe kept in regs ----
#pragma unroll
    for (int n = 0; n < NSAMP; n++) {
        float pr0 = __shfl(pl, n * 3 + 0, 64) - pi0;
        float pr1 = __shfl(pl, n * 3 + 1, 64) - pi1;
        float pr2 = __shfl(pl, n * 3 + 2, 64) - pi2;
        float h0 = fmaxf(fmaf(pr2, wp1f[6], fmaf(pr1, wp1f[3], fmaf(pr0, wp1f[0], bp1f[0]))), 0.0f);
        float h1 = fmaxf(fmaf(pr2, wp1f[7], fmaf(pr1, wp1f[4], fmaf(pr0, wp1f[1], bp1f[1]))), 0.0f);
        float h2 = fmaxf(fmaf(pr2, wp1f[8], fmaf(pr1, wp1f[5], fmaf(pr0, wp1f[2], bp1f[2]))), 0.0f);
        float pe = fmaf(h2, wp2c2, fmaf(h1, wp2c1, fmaf(h0, wp2c0, bp2c)));
        float kk = lo2f(kvw[n]);
        float vv = hi2f(kvw[n]);
        wvbuf[pt][n * 68 + c] = fmaxf(fmaf(kk - qq + pe, g1c, bb1c), 0.0f);
        pv[n] = vv + pe;
    }
    __syncthreads();

    // ---- stage 2: a[n][s] = ba[s] + sum_c wv[n][c]*Wa[c][s]; tb = relu(bn2) ----
#pragma unroll
    for (int rep = 0; rep < 2; rep++) {
        int T = c + rep * 64;
        int n = T >> 3, s = T & 7;
        float a = cw[OFF_BA + s];
#pragma unroll
        for (int c4 = 0; c4 < 16; c4++) {
            float4 w4 = *((const float4*)&wvbuf[pt][n * 68 + c4 * 4]);
            a = fmaf(w4.x, cw[OFF_WA + (c4 * 4 + 0) * 8 + s], a);
            a = fmaf(w4.y, cw[OFF_WA + (c4 * 4 + 1) * 8 + s], a);
            a = fmaf(w4.z, cw[OFF_WA + (c4 * 4 + 2) * 8 + s], a);
            a = fmaf(w4.w, cw[OFF_WA + (c4 * 4 + 3) * 8 + s], a);
        }
        tbbuf[pt][n * 8 + s] = fmaxf(fmaf(a, cw[OFF_G2 + s] * rs, cw[OFF_BB2 + s]), 0.0f);
    }
    __syncthreads();

    // ---- stage 3: logits w2[n][t] = bw[t] + sum_s tb[n][s]*Wb[s][t] ----
#pragma unroll
    for (int rep = 0; rep < 2; rep++) {
        int T = c + rep * 64;
        int n = T >> 3, t = T & 7;
        float w2 = cw[OFF_BW + t];
#pragma unroll
        for (int s = 0; s < 8; s++)
            w2 = fmaf(tbbuf[pt][n * 8 + s], cw[OFF_WB + s * 8 + t], w2);
        w2buf[pt][n * 8 + t] = w2;
    }
    __syncthreads();

    // ---- stage 4: softmax over neighbors per attention channel t (lanes 0..7) ----
    if (c < 8) {
        float mx = -1e30f;
#pragma unroll
        for (int n = 0; n < NSAMP; n++) mx = fmaxf(mx, w2buf[pt][n * 8 + c]);
        float sm = 0.0f;
        float e[NSAMP];
#pragma unroll
        for (int n = 0; n < NSAMP; n++) { e[n] = __expf(w2buf[pt][n * 8 + c] - mx); sm += e[n]; }
        float inv = 1.0f / sm;
#pragma unroll
        for (int n = 0; n < NSAMP; n++) w2buf[pt][n * 8 + c] = e[n] * inv;
    }
    __syncthreads();

    // ---- stage 5: out[c] = sum_n pv[n] * w[n][c&7] ----
    const int t = c & 7;
    float o = 0.0f;
#pragma unroll
    for (int n = 0; n < NSAMP; n++)
        o = fmaf(pv[n], w2buf[pt][n * 8 + t], o);
    if (isf32) ((float*)OUT)[(size_t)i * 64 + c] = o;
    else       ((__hip_bfloat16*)OUT)[(size_t)i * 64 + c] = __float2bfloat16(o);
}

// ---------------------------------------------------------------------------
extern "C" void kernel_launch(void* const* d_in, const int* in_sizes, int n_in,
                              void* d_out, int out_size, void* d_ws, size_t ws_size,
                              hipStream_t stream)
{
    const u16* p   = (const u16*)d_in[0];
    const u16* x   = (const u16*)d_in[1];
    const int* idx = (const int*)d_in[2];

    // workspace layout: cw 64KB + Q 25.6MB + KV 25.6MB = 51.3 MB (< proven 76.9)
    float* cw = (float*)d_ws;                 // 64 KB
    float* Q  = cw + CW_PAD;                  // N*64 f32 = 25.6 MB
    u32*   KV = (u32*)(Q + (size_t)N_PTS * 64); // N*64 u32 = 25.6 MB

    convert_kernel<<<8, 256, 0, stream>>>(
        x,
        d_in[3],  d_in[4],  d_in[5],  d_in[6],  d_in[7],  d_in[8],
        d_in[9],  d_in[10], d_in[11], d_in[12], d_in[13], d_in[14],
        d_in[15], d_in[16], d_in[17], d_in[18], d_in[19], d_in[20],
        d_in[21], d_in[22], cw);
    qkv_mfma_kernel<<<1250, 256, 0, stream>>>(x, cw, Q, KV);  // 1250*5*16 = 100000
    attn_kernel<<<N_PTS / 4, 256, 0, stream>>>(p, idx, x, cw, Q, KV, d_out);
}

// Round 4
// 353.002 us; speedup vs baseline: 1.6143x; 1.0400x over previous
//
#include <hip/hip_runtime.h>
#include <hip/hip_bf16.h>

typedef unsigned int u32;
typedef unsigned short u16;
typedef __attribute__((ext_vector_type(8))) short short8;   // 8 bf16 (4 VGPRs)
typedef __attribute__((ext_vector_type(4))) float f32x4;    // MFMA C/D

#define N_PTS 100000
#define NSAMP 16

__device__ __forceinline__ float lo2f(u32 u){ return __uint_as_float(u << 16); }
__device__ __forceinline__ float hi2f(u32 u){ return __uint_as_float(u & 0xffff0000u); }
__device__ __forceinline__ float us2f(u16 u){ return __uint_as_float(((u32)u) << 16); }

// round-to-nearest-even f32 -> bf16 bits (finite values only)
__device__ __forceinline__ u16 f2bf(float f) {
    u32 u = __float_as_uint(f);
    return (u16)((u + 0x7fffu + ((u >> 16) & 1u)) >> 16);
}
__device__ __forceinline__ u32 pack2(float k, float v) {
    return (u32)f2bf(k) | ((u32)f2bf(v) << 16);
}

// Runtime input-dtype probe (must be called by ALL threads of the block).
__device__ __forceinline__ bool detect_f32(const u16* __restrict__ xprobe) {
    float f = us2f(xprobe[(threadIdx.x & 63) * 2]);
    int cnt = __syncthreads_count(fabsf(f) > 1024.0f ? 1 : 0);
    return cnt >= 8;
}

// canonical fp32 weight-block offsets (floats, each 16B-aligned)
#define OFF_WQ   0
#define OFF_BQ   4096
#define OFF_WK   4160
#define OFF_BK   8256
#define OFF_WV   8320
#define OFF_BV   12416
#define OFF_WP1  12480
#define OFF_BP1  12492
#define OFF_GP   12496
#define OFF_BP   12500
#define OFF_WP2  12504
#define OFF_BP2  12696
#define OFF_G1   12760
#define OFF_BB1  12824
#define OFF_WA   12888
#define OFF_BA   13400
#define OFF_G2   13408
#define OFF_BB2  13416
#define OFF_WB   13424
#define OFF_BW   13488
#define FRAG_OFF 13504   /* bf16 frag blob: 2 planes x 12288 u16 = 12288 floats */
#define CW_PAD   32768   /* pad region to 128 KB of floats */

// ---------------------------------------------------------------------------
// K0: canonicalize weights to fp32 + build pre-transposed bf16 hi/lo MFMA
// B-fragment blob for the QKV kernel (removes per-wave setup there).
// Blob layout (u16): fb[plane][m][kh][w][l][j], plane-major 12288 each.
//   value = W_m[(kh*32+(l>>4)*8+j)*64 + (w*16+(l&15))]; hi=f2bf(v), lo=f2bf(v-hi)
// ---------------------------------------------------------------------------
__global__ __launch_bounds__(256) void convert_kernel(
    const u16* __restrict__ xprobe,
    const void* s0,  const void* s1,  const void* s2,  const void* s3,
    const void* s4,  const void* s5,  const void* s6,  const void* s7,
    const void* s8,  const void* s9,  const void* s10, const void* s11,
    const void* s12, const void* s13, const void* s14, const void* s15,
    const void* s16, const void* s17, const void* s18, const void* s19,
    float* __restrict__ cw)
{
    bool isf32 = detect_f32(xprobe);
    const void* srcs[20] = {s0,s1,s2,s3,s4,s5,s6,s7,s8,s9,s10,s11,s12,s13,s14,s15,s16,s17,s18,s19};
    const int sizes[20] = {4096,64,4096,64,4096,64,9,3,3,3,192,64,64,64,512,8,8,8,64,8};
    const int offs[20]  = {OFF_WQ,OFF_BQ,OFF_WK,OFF_BK,OFF_WV,OFF_BV,OFF_WP1,OFF_BP1,OFF_GP,OFF_BP,
                           OFF_WP2,OFF_BP2,OFF_G1,OFF_BB1,OFF_WA,OFF_BA,OFF_G2,OFF_BB2,OFF_WB,OFF_BW};
    int tid = threadIdx.x + blockIdx.x * 256;
    int stride = gridDim.x * 256;
    for (int a = 0; a < 20; a++) {
        const void* s = srcs[a];
        for (int k = tid; k < sizes[a]; k += stride)
            cw[offs[a] + k] = isf32 ? ((const float*)s)[k] : us2f(((const u16*)s)[k]);
    }

    // frag blob (reads raw weight srcs directly -> no cross-block dependency)
    u16* fb = (u16*)(cw + FRAG_OFF);
    for (int t = tid; t < 24576; t += stride) {
        int plane = t / 12288, r = t - plane * 12288;
        int m  = r >> 12;           // 0..2
        int r2 = r & 4095;
        int kh = r2 >> 11;
        int r3 = r2 & 2047;
        int w  = r3 >> 9;
        int r4 = r3 & 511;
        int l  = r4 >> 3, j = r4 & 7;
        int k  = kh * 32 + (l >> 4) * 8 + j;
        int nc = w * 16 + (l & 15);
        int si = k * 64 + nc;
        const void* s = (m == 0) ? s0 : ((m == 1) ? s2 : s4);
        float val = isf32 ? ((const float*)s)[si] : us2f(((const u16*)s)[si]);
        u16 hb = f2bf(val);
        fb[t] = (plane == 0) ? hb : f2bf(val - us2f(hb));
    }
}

// ---------------------------------------------------------------------------
// K1: MFMA QKV projection.  x[100000,64] @ {Wq|Wk|Wv}[64,192] + bias.
// B-frags now loaded from the pre-built blob (24 coalesced 16B loads, no
// VALU); A-tile loads double-buffered across the 5-tile loop.
// A/B share k-mapping k=(l>>4)*8+j (cancels); C/D: col=l&15, row=(l>>4)*4+r
// (validated by round-3 pass). Grid 1250 x 5 tiles x 16 rows = 100000.
// ---------------------------------------------------------------------------
#define QKV_TPB 5
__global__ __launch_bounds__(256) void qkv_mfma_kernel(
    const u16* __restrict__ xraw, const float* __restrict__ cw,
    float* __restrict__ Q, u32* __restrict__ KV)
{
    bool isf32 = detect_f32(xraw);
    const int w   = threadIdx.x >> 6;
    const int l   = threadIdx.x & 63;
    const int col = l & 15;
    const int g   = l >> 4;

    // ---- B fragments from blob ----
    const u16* fbh = (const u16*)(cw + FRAG_OFF);
    const u16* fbl = fbh + 12288;
    short8 bh[3][2], bl[3][2];
#pragma unroll
    for (int m = 0; m < 3; m++)
#pragma unroll
        for (int kh = 0; kh < 2; kh++) {
            int o = (((m * 2 + kh) * 4 + w) * 64 + l) * 8;
            bh[m][kh] = *(const short8*)(fbh + o);
            bl[m][kh] = *(const short8*)(fbl + o);
        }
    const float bqc = cw[OFF_BQ + w * 16 + col];
    const float bkc = cw[OFF_BK + w * 16 + col];
    const float bvc = cw[OFF_BV + w * 16 + col];

    // A loader: fills ah[2] (+ al[2] when fp32 input)
#define LOAD_A(IT, AH, AL)                                                        \
    {                                                                             \
        const int M0_ = (blockIdx.x * QKV_TPB + (IT)) * 16;                       \
        if (isf32) {                                                              \
            const float4* xf = (const float4*)xraw;                               \
            _Pragma("unroll")                                                     \
            for (int kh = 0; kh < 2; kh++) {                                      \
                float4 f0 = xf[(size_t)(M0_ + col) * 16 + kh * 8 + g * 2];        \
                float4 f1 = xf[(size_t)(M0_ + col) * 16 + kh * 8 + g * 2 + 1];    \
                float ff[8] = {f0.x, f0.y, f0.z, f0.w, f1.x, f1.y, f1.z, f1.w};   \
                _Pragma("unroll")                                                 \
                for (int j = 0; j < 8; j++) {                                     \
                    u16 hb_ = f2bf(ff[j]);                                        \
                    AH[kh][j] = (short)hb_;                                       \
                    AL[kh][j] = (short)f2bf(ff[j] - us2f(hb_));                   \
                }                                                                 \
            }                                                                     \
        } else {                                                                  \
            const short8* xb = (const short8*)xraw;                               \
            _Pragma("unroll")                                                     \
            for (int kh = 0; kh < 2; kh++)                                        \
                AH[kh] = xb[(size_t)(M0_ + col) * 8 + kh * 4 + g];                \
        }                                                                         \
    }

    short8 ahA[2], alA[2], ahB[2], alB[2];
    LOAD_A(0, ahA, alA);

#pragma unroll
    for (int it = 0; it < QKV_TPB; it++) {
        short8 (&ah)[2] = (it & 1) ? ahB : ahA;   // it is compile-time (unrolled)
        short8 (&al)[2] = (it & 1) ? alB : alA;
        short8 (&ahN)[2] = (it & 1) ? ahA : ahB;
        short8 (&alN)[2] = (it & 1) ? alA : alB;
        if (it + 1 < QKV_TPB) LOAD_A(it + 1, ahN, alN);

        const int M0 = (blockIdx.x * QKV_TPB + it) * 16;
        f32x4 aQ = {bqc, bqc, bqc, bqc};
        f32x4 aK = {bkc, bkc, bkc, bkc};
        f32x4 aV = {bvc, bvc, bvc, bvc};

#pragma unroll
        for (int kh = 0; kh < 2; kh++) {
            aQ = __builtin_amdgcn_mfma_f32_16x16x32_bf16(ah[kh], bh[0][kh], aQ, 0, 0, 0);
            aK = __builtin_amdgcn_mfma_f32_16x16x32_bf16(ah[kh], bh[1][kh], aK, 0, 0, 0);
            aV = __builtin_amdgcn_mfma_f32_16x16x32_bf16(ah[kh], bh[2][kh], aV, 0, 0, 0);
            aQ = __builtin_amdgcn_mfma_f32_16x16x32_bf16(ah[kh], bl[0][kh], aQ, 0, 0, 0);
            aK = __builtin_amdgcn_mfma_f32_16x16x32_bf16(ah[kh], bl[1][kh], aK, 0, 0, 0);
            aV = __builtin_amdgcn_mfma_f32_16x16x32_bf16(ah[kh], bl[2][kh], aV, 0, 0, 0);
            if (isf32) {
                aQ = __builtin_amdgcn_mfma_f32_16x16x32_bf16(al[kh], bh[0][kh], aQ, 0, 0, 0);
                aK = __builtin_amdgcn_mfma_f32_16x16x32_bf16(al[kh], bh[1][kh], aK, 0, 0, 0);
                aV = __builtin_amdgcn_mfma_f32_16x16x32_bf16(al[kh], bh[2][kh], aV, 0, 0, 0);
            }
        }

#pragma unroll
        for (int r = 0; r < 4; r++) {
            int row = M0 + g * 4 + r;
            Q [(size_t)row * 64 + w * 16 + col] = aQ[r];
            KV[(size_t)row * 64 + w * 16 + col] = pack2(aK[r], aV[r]);
        }
    }
#undef LOAD_A
}

// ---------------------------------------------------------------------------
// K2: fused attention. 4 waves = 4 points per block; lane = channel c.
// Round-4 changes: (1) h-MLP computed once by lanes 0..47 into hbuf (was
// recomputed by all 64 lanes per neighbor + 48 bpermutes), (2) neighbor
// indices moved to SGPRs via readlane -> gather addressing on SALU,
// (3) stage-4 softmax parallelized across all 64 lanes via shfl_xor.
// ---------------------------------------------------------------------------
__global__ __launch_bounds__(256) void attn_kernel(
    const u16* __restrict__ P, const int* __restrict__ IDX,
    const u16* __restrict__ xprobe, const float* __restrict__ cw,
    const float* __restrict__ Q, const u32* __restrict__ KV,
    void* __restrict__ OUT)
{
    __shared__ __align__(16) float wvbuf[4][NSAMP * 68];  // relu(bn1(w)), stride 68
    __shared__ __align__(16) float tbbuf[4][NSAMP * 8];   // relu(bn2(.@Wa+ba))
    __shared__ __align__(16) float w2buf[4][NSAMP * 8];   // logits -> softmax wts
    __shared__ __align__(16) float hbuf[4][NSAMP * 4];    // h[n][d], d<3 used

    bool isf32 = detect_f32(xprobe);

    const int pt = threadIdx.x >> 6;
    const int c  = threadIdx.x & 63;
    const int i  = blockIdx.x * 4 + pt;        // grid*4 == N_PTS exactly
    const float rs = 1.0f / sqrtf(1.0f + 1e-5f);

    // ---- neighbor indices (lane n<16 holds j_n), then all 16 gathers ----
    const int jv = IDX[(size_t)i * NSAMP + (c & 15)];

    u32 kvw[NSAMP];
    const u32* KVc = KV + c;
#pragma unroll
    for (int n = 0; n < NSAMP; n++) {
        int j = __builtin_amdgcn_readlane(jv, n);   // SGPR -> SALU addressing
        kvw[n] = KVc[(size_t)j << 6];
    }

    const float qq = Q[(size_t)i * 64 + c];

    // ---- distributed h-MLP: lane (n,d) = (c/3, c%3) computes h[n][d] ----
    const float* Pf = (const float*)P;
    const int n_p  = c / 3;
    const int d_p  = c - n_p * 3;
    const int np15 = n_p & 15;
    const int j_p  = __shfl(jv, np15, 64);
    float pj, pid;
    if (isf32) { pj = Pf[(size_t)j_p * 3 + d_p]; pid = Pf[(size_t)i * 3 + d_p]; }
    else       { pj = us2f(P[(size_t)j_p * 3 + d_p]); pid = us2f(P[(size_t)i * 3 + d_p]); }
    const float pr = pj - pid;
    const int lb = np15 * 3;
    const float prD0 = __shfl(pr, lb + 0, 64);
    const float prD1 = __shfl(pr, lb + 1, 64);
    const float prD2 = __shfl(pr, lb + 2, 64);
    {
        float gd  = cw[OFF_GP + d_p] * rs;
        float w0s = cw[OFF_WP1 + 0 * 3 + d_p] * gd;
        float w1s = cw[OFF_WP1 + 1 * 3 + d_p] * gd;
        float w2s = cw[OFF_WP1 + 2 * 3 + d_p] * gd;
        float bs  = cw[OFF_BP1 + d_p] * gd + cw[OFF_BP + d_p];
        float h = fmaf(prD2, w2s, fmaf(prD1, w1s, fmaf(prD0, w0s, bs)));
        h = fmaxf(h, 0.0f);
        if (c < 48) hbuf[pt][np15 * 4 + d_p] = h;
    }
    asm volatile("s_waitcnt lgkmcnt(0)" ::: "memory");  // wave-local LDS RAW

    // per-lane channel constants (L1/L2-hot)
    const float wp2c0 = cw[OFF_WP2 + 0 * 64 + c];
    const float wp2c1 = cw[OFF_WP2 + 1 * 64 + c];
    const float wp2c2 = cw[OFF_WP2 + 2 * 64 + c];
    const float bp2c  = cw[OFF_BP2 + c];
    const float g1c   = cw[OFF_G1  + c] * rs;
    const float bb1c  = cw[OFF_BB1 + c];

    float pv[NSAMP];

    // ---- stage 1: per-(n,c) relation input into LDS; v+pe kept in regs ----
#pragma unroll
    for (int n = 0; n < NSAMP; n++) {
        float4 hb = *((const float4*)&hbuf[pt][n * 4]);
        float pe = fmaf(hb.z, wp2c2, fmaf(hb.y, wp2c1, fmaf(hb.x, wp2c0, bp2c)));
        float kk = lo2f(kvw[n]);
        float vv = hi2f(kvw[n]);
        wvbuf[pt][n * 68 + c] = fmaxf(fmaf(kk - qq + pe, g1c, bb1c), 0.0f);
        pv[n] = vv + pe;
    }
    __syncthreads();

    // ---- stage 2: a[n][s] = ba[s] + sum_c wv[n][c]*Wa[c][s]; tb = relu(bn2) ----
#pragma unroll
    for (int rep = 0; rep < 2; rep++) {
        int T = c + rep * 64;
        int n = T >> 3, s = T & 7;
        float a = cw[OFF_BA + s];
#pragma unroll
        for (int c4 = 0; c4 < 16; c4++) {
            float4 w4 = *((const float4*)&wvbuf[pt][n * 68 + c4 * 4]);
            a = fmaf(w4.x, cw[OFF_WA + (c4 * 4 + 0) * 8 + s], a);
            a = fmaf(w4.y, cw[OFF_WA + (c4 * 4 + 1) * 8 + s], a);
            a = fmaf(w4.z, cw[OFF_WA + (c4 * 4 + 2) * 8 + s], a);
            a = fmaf(w4.w, cw[OFF_WA + (c4 * 4 + 3) * 8 + s], a);
        }
        tbbuf[pt][n * 8 + s] = fmaxf(fmaf(a, cw[OFF_G2 + s] * rs, cw[OFF_BB2 + s]), 0.0f);
    }
    __syncthreads();

    // ---- stage 3: logits w2[n][t] = bw[t] + sum_s tb[n][s]*Wb[s][t] ----
#pragma unroll
    for (int rep = 0; rep < 2; rep++) {
        int T = c + rep * 64;
        int n = T >> 3, t = T & 7;
        float w2 = cw[OFF_BW + t];
#pragma unroll
        for (int s = 0; s < 8; s++)
            w2 = fmaf(tbbuf[pt][n * 8 + s], cw[OFF_WB + s * 8 + t], w2);
        w2buf[pt][n * 8 + t] = w2;
    }
    __syncthreads();

    // ---- stage 4: softmax over n per channel t — all 64 lanes active ----
    {
        const int t4 = c & 7, n4 = c >> 3;     // lane handles n4 and n4+8
        float l0 = w2buf[pt][n4 * 8 + t4];
        float l1 = w2buf[pt][(n4 + 8) * 8 + t4];
        float m = fmaxf(l0, l1);
        m = fmaxf(m, __shfl_xor(m, 8, 64));
        m = fmaxf(m, __shfl_xor(m, 16, 64));
        m = fmaxf(m, __shfl_xor(m, 32, 64));
        float e0 = __expf(l0 - m), e1 = __expf(l1 - m);
        float s = e0 + e1;
        s += __shfl_xor(s, 8, 64);
        s += __shfl_xor(s, 16, 64);
        s += __shfl_xor(s, 32, 64);
        float inv = 1.0f / s;
        w2buf[pt][n4 * 8 + t4] = e0 * inv;
        w2buf[pt][(n4 + 8) * 8 + t4] = e1 * inv;
    }
    __syncthreads();

    // ---- stage 5: out[c] = sum_n pv[n] * w[n][c&7] ----
    const int t = c & 7;
    float o = 0.0f;
#pragma unroll
    for (int n = 0; n < NSAMP; n++)
        o = fmaf(pv[n], w2buf[pt][n * 8 + t], o);
    if (isf32) ((float*)OUT)[(size_t)i * 64 + c] = o;
    else       ((__hip_bfloat16*)OUT)[(size_t)i * 64 + c] = __float2bfloat16(o);
}

// ---------------------------------------------------------------------------
extern "C" void kernel_launch(void* const* d_in, const int* in_sizes, int n_in,
                              void* d_out, int out_size, void* d_ws, size_t ws_size,
                              hipStream_t stream)
{
    const u16* p   = (const u16*)d_in[0];
    const u16* x   = (const u16*)d_in[1];
    const int* idx = (const int*)d_in[2];

    // workspace layout: cw 128KB + Q 25.6MB + KV 25.6MB ≈ 51.4 MB
    float* cw = (float*)d_ws;                   // 128 KB (incl. frag blob)
    float* Q  = cw + CW_PAD;                    // N*64 f32 = 25.6 MB
    u32*   KV = (u32*)(Q + (size_t)N_PTS * 64); // N*64 u32 = 25.6 MB

    convert_kernel<<<16, 256, 0, stream>>>(
        x,
        d_in[3],  d_in[4],  d_in[5],  d_in[6],  d_in[7],  d_in[8],
        d_in[9],  d_in[10], d_in[11], d_in[12], d_in[13], d_in[14],
        d_in[15], d_in[16], d_in[17], d_in[18], d_in[19], d_in[20],
        d_in[21], d_in[22], cw);
    qkv_mfma_kernel<<<1250, 256, 0, stream>>>(x, cw, Q, KV);  // 1250*5*16 = 100000
    attn_kernel<<<N_PTS / 4, 256, 0, stream>>>(p, idx, x, cw, Q, KV, d_out);
}